// Round 2
// baseline (796.863 us; speedup 1.0000x reference)
//
#include <hip/hip_runtime.h>

// L2Similarity: out[n][m] = -||x_n - g_m||  for x:[8192,128] f32, g:[16384,128] f32
// = -sqrt(max(||x||^2 + ||g||^2 - 2 x.g, 0))
// NT GEMM via bf16 MFMA (inline f32->bf16 RNE), exact f32 norms, fused epilogue.
// R2 changes vs R1: (1) plain stores — nontemporal stores bypassed L2 and raced
// the harness poison-memset lines (post-timing divergence) and killed store BW;
// (2) per-half norm slots (no LDS read-modify-write); (3) launch_bounds (256,2)
// so the 64 acc + 32 frag VGPRs don't spill under a 128-reg cap.

#define N_IMG 8192
#define N_GTS 16384
#define K_DIM 128
#define BM 128
#define BN 128
#define LDS_K 64      // K staged per half
#define LDAH 72       // 64 + 8 pad (row stride 144B: 16B-aligned rows, 4-bank shift/row)

typedef __attribute__((ext_vector_type(8))) short short8;   // 8 bf16 = 4 VGPRs
typedef __attribute__((ext_vector_type(4))) float f32x4;

__device__ __forceinline__ unsigned short f2bf(float x) {
    unsigned int u = __float_as_uint(x);
    u += 0x7FFFu + ((u >> 16) & 1u);
    return (unsigned short)(u >> 16);
}

__global__ __launch_bounds__(256, 2)
void l2sim_kernel(const float* __restrict__ A, const float* __restrict__ G,
                  float* __restrict__ out)
{
    __shared__ short a_s[BM][LDAH];
    __shared__ short b_s[BN][LDAH];
    __shared__ float xsq_s[2][BM];   // per-half partial row norms (no RMW)
    __shared__ float gsq_s[2][BN];

    const int t  = threadIdx.x;
    const int bm = blockIdx.y;   // 0..63   image-row tile
    const int bn = blockIdx.x;   // 0..127  gts-row tile

    const int wave = t >> 6;         // 4 waves, 2x2 over the 128x128 tile
    const int lane = t & 63;
    const int wm   = (wave & 1) << 6;
    const int wn   = (wave >> 1) << 6;
    const int lm   = lane & 15;      // MFMA m/n index within 16-tile
    const int quad = lane >> 4;      // 0..3

    f32x4 acc[4][4] = {};            // [mi][ni]

    #pragma unroll
    for (int h = 0; h < 2; ++h) {
        if (h) __syncthreads();      // protect LDS tiles from previous half's readers

        // ---- stage A half: 128 rows x 64 K, f32->bf16, exact f32 partial sumsq ----
        {
            const float* gA = A + (size_t)bm * BM * K_DIM + h * LDS_K;
            #pragma unroll
            for (int i = 0; i < 8; ++i) {
                int f   = i * 256 + t;     // float4 index in 128x64 half-tile
                int row = f >> 4;          // 16 float4 per row
                int c4  = f & 15;
                float4 v = *(const float4*)(gA + (size_t)row * K_DIM + c4 * 4);
                float s = v.x*v.x + v.y*v.y + v.z*v.z + v.w*v.w;
                s += __shfl_down(s, 8, 16);
                s += __shfl_down(s, 4, 16);
                s += __shfl_down(s, 2, 16);
                s += __shfl_down(s, 1, 16);
                short4 bv;
                bv.x = (short)f2bf(v.x);
                bv.y = (short)f2bf(v.y);
                bv.z = (short)f2bf(v.z);
                bv.w = (short)f2bf(v.w);
                *(short4*)&a_s[row][c4 * 4] = bv;
                if ((t & 15) == 0) xsq_s[h][row] = s;   // plain store, one writer
            }
        }
        // ---- stage B half ----
        {
            const float* gB = G + (size_t)bn * BN * K_DIM + h * LDS_K;
            #pragma unroll
            for (int i = 0; i < 8; ++i) {
                int f   = i * 256 + t;
                int row = f >> 4;
                int c4  = f & 15;
                float4 v = *(const float4*)(gB + (size_t)row * K_DIM + c4 * 4);
                float s = v.x*v.x + v.y*v.y + v.z*v.z + v.w*v.w;
                s += __shfl_down(s, 8, 16);
                s += __shfl_down(s, 4, 16);
                s += __shfl_down(s, 2, 16);
                s += __shfl_down(s, 1, 16);
                short4 bv;
                bv.x = (short)f2bf(v.x);
                bv.y = (short)f2bf(v.y);
                bv.z = (short)f2bf(v.z);
                bv.w = (short)f2bf(v.w);
                *(short4*)&b_s[row][c4 * 4] = bv;
                if ((t & 15) == 0) gsq_s[h][row] = s;
            }
        }
        __syncthreads();

        // ---- MFMA: 2 k-steps of 32 per half; wave does 4x4 16x16 tiles ----
        #pragma unroll
        for (int ks = 0; ks < 2; ++ks) {
            short8 af[4], bfr[4];
            #pragma unroll
            for (int mi = 0; mi < 4; ++mi)
                af[mi] = *(const short8*)&a_s[wm + mi * 16 + lm][ks * 32 + quad * 8];
            #pragma unroll
            for (int ni = 0; ni < 4; ++ni)
                bfr[ni] = *(const short8*)&b_s[wn + ni * 16 + lm][ks * 32 + quad * 8];
            #pragma unroll
            for (int mi = 0; mi < 4; ++mi)
                #pragma unroll
                for (int ni = 0; ni < 4; ++ni)
                    acc[mi][ni] = __builtin_amdgcn_mfma_f32_16x16x32_bf16(
                        af[mi], bfr[ni], acc[mi][ni], 0, 0, 0);
        }
    }

    // ---- epilogue: d2 = xsq + gsq - 2*dot; out = -sqrt(max(d2,0)) ----
    // C/D layout: col = lane&15 (N), row = quad*4 + reg (M)
    float* outBase = out + (size_t)bm * BM * N_GTS + (size_t)bn * BN;
    #pragma unroll
    for (int mi = 0; mi < 4; ++mi) {
        #pragma unroll
        for (int r = 0; r < 4; ++r) {
            int m_loc = wm + mi * 16 + quad * 4 + r;
            float xs = xsq_s[0][m_loc] + xsq_s[1][m_loc];
            float* orow = outBase + (size_t)m_loc * N_GTS;
            #pragma unroll
            for (int ni = 0; ni < 4; ++ni) {
                int n_loc = wn + ni * 16 + lm;
                float gs = gsq_s[0][n_loc] + gsq_s[1][n_loc];
                float d2 = fmaxf(xs + gs - 2.0f * acc[mi][ni][r], 0.0f);
                orow[n_loc] = -sqrtf(d2);
            }
        }
    }
}

extern "C" void kernel_launch(void* const* d_in, const int* in_sizes, int n_in,
                              void* d_out, int out_size, void* d_ws, size_t ws_size,
                              hipStream_t stream) {
    const float* A = (const float*)d_in[0];   // image_features [8192,128]
    const float* G = (const float*)d_in[1];   // gts            [16384,128]
    float* out = (float*)d_out;               // [8192,16384]
    dim3 grid(N_GTS / BN, N_IMG / BM);        // (128, 64)
    l2sim_kernel<<<grid, 256, 0, stream>>>(A, G, out);
}